// Round 14
// baseline (2035.889 us; speedup 1.0000x reference)
//
#include <hip/hip_runtime.h>
#include <hip/hip_bf16.h>

// Problem constants
#define SEQL 4096
#define VECT 300
#define DP   320     // padded feature dim (k-dim), 10 chunks of 32
#define NQT  20      // n-tiles (320 cols) for projection GEMMs
#define HN   128
#define G3   384     // 3*H
#define JC   4       // flash j-chunks (split-K over key dim)
#define KROW 328     // LDS K-tile row stride (u16)
#define VROW 40      // LDS VT-tile row stride (u16)
#define PROW 40      // pbuf row stride
#define AROW 328     // fused-kernel LDS A-tile row stride (u16)

typedef unsigned short u16;
typedef unsigned char  u8;
typedef __attribute__((ext_vector_type(8))) short bf16x8;  // 8 bf16 = 4 VGPRs
typedef __attribute__((ext_vector_type(4))) float f32x4;
typedef __attribute__((ext_vector_type(4))) unsigned int u32x4;
typedef __attribute__((ext_vector_type(8))) int   v8i;     // 8 dwords (fp8 x32)

#define MFMA(a,b,c) __builtin_amdgcn_mfma_f32_16x16x32_bf16(a,b,c,0,0,0)
// Verified layouts (learn_hip m89/m91/m120):
//   A[m][k]: m=lane&15, k=(lane>>4)*8+j
//   B[k][n]: n=lane&15, k=(lane>>4)*8+j
//   C/D[row][col]: col=lane&15, row=(lane>>4)*4+reg

#define L2E 1.44269504088896f

#define RAW_BAR() do {                                          \
    asm volatile("s_waitcnt lgkmcnt(0)" ::: "memory");          \
    __builtin_amdgcn_s_barrier();                               \
    asm volatile("" ::: "memory");                              \
} while (0)

__device__ __forceinline__ float bf2f(u16 v){
    union { unsigned u; float f; } t; t.u = ((unsigned)v) << 16; return t.f;
}
__device__ __forceinline__ u16 f2bf(float f){
    union { float f; unsigned u; } t; t.f = f;
    return (u16)((t.u + 0x7FFFu + ((t.u >> 16) & 1u)) >> 16);
}
__device__ __forceinline__ float sigm_f(float x){
    return __builtin_amdgcn_rcpf(1.f + __builtin_amdgcn_exp2f(-L2E * x));
}
__device__ __forceinline__ float tanh_f(float x){
    return fmaf(2.f, __builtin_amdgcn_rcpf(1.f + __builtin_amdgcn_exp2f(-2.f * L2E * x)), -1.f);
}
__device__ __forceinline__ float sel4(f32x4 v, int r){
    float a = (r & 1) ? v.y : v.x;
    float b = (r & 1) ? v.w : v.z;
    return (r & 2) ? b : a;
}

// ---------------- fused prep: x pad (y selects seq)
__global__ __launch_bounds__(256) void pad_x2(const float* __restrict__ x1, const float* __restrict__ x2,
                                              float* __restrict__ xf, u16* __restrict__ cur)
{
    int s = blockIdx.y;
    const float* src = s ? x2 : x1;
    float* xfo = xf + (long)s * SEQL * DP;
    u16*  cro = cur + (long)s * SEQL * DP;
    int n = SEQL * DP;
    for (int i = blockIdx.x * blockDim.x + threadIdx.x; i < n; i += gridDim.x * blockDim.x){
        int r = i / DP, c = i - r * DP;
        float v = (c < VECT) ? src[r * VECT + c] : 0.f;
        xfo[i] = v;
        cro[i] = f2bf(v);
    }
}

// ---------------- fused prep: 3 attention weights (q,k,v) -> Wpk (y selects which)
__global__ __launch_bounds__(256) void cvt_pad_w3(const float* __restrict__ w0, const float* __restrict__ w1,
                                                  const float* __restrict__ w2,
                                                  u16* __restrict__ Wpk)
{
    int sl = blockIdx.y;
    const float* src = (sl == 0) ? w0 : (sl == 1) ? w1 : w2;
    u16* dst = Wpk + (long)sl * DP * DP;
    int n = DP * DP;
    for (int i = blockIdx.x * blockDim.x + threadIdx.x; i < n; i += gridDim.x * blockDim.x){
        int r = i / DP, c = i - r * DP;
        float v = (r < VECT && c < VECT) ? src[r * VECT + c] : 0.f;
        dst[i] = f2bf(v);
    }
}

// ---------------- prep: W' = aln_g ⊙ w_w (bf16 padded), gWsum[out] = Σ_c g*w,
// bW[out] = Σ_c aln_b*w. Block 320 (=DP, 5 waves), grid 320 (one out per block).
__global__ __launch_bounds__(320) void prep_wln(const float* __restrict__ w_w,
                                                const float* __restrict__ ag, const float* __restrict__ ab,
                                                u16* __restrict__ WLN,
                                                float* __restrict__ gWsum, float* __restrict__ bW)
{
    int out = blockIdx.x;
    int c   = threadIdx.x;
    float wv = (out < VECT && c < VECT) ? w_w[out * VECT + c] : 0.f;
    float gv = (c < VECT) ? ag[c] : 0.f;
    float bv = (c < VECT) ? ab[c] : 0.f;
    float wp = gv * wv;
    WLN[(long)out * DP + c] = f2bf(wp);
    float s1 = wp, s2 = bv * wv;
    #pragma unroll
    for (int o = 1; o < 64; o <<= 1){ s1 += __shfl_xor(s1, o); s2 += __shfl_xor(s2, o); }
    __shared__ float r1[5], r2[5];
    if ((c & 63) == 0){ r1[c >> 6] = s1; r2[c >> 6] = s2; }
    __syncthreads();
    if (c == 0){
        float a = 0.f, b2 = 0.f;
        #pragma unroll
        for (int i = 0; i < 5; i++){ a += r1[i]; b2 += r2[i]; }
        gWsum[out] = a; bW[out] = b2;
    }
}

// ---------------- fused prep: 2 GRU input weights -> GWpk (y selects)
__global__ __launch_bounds__(256) void cvt_pad_g2(const float* __restrict__ w0, const float* __restrict__ w1,
                                                  u16* __restrict__ GWpk)
{
    int s = blockIdx.y;
    const float* src = s ? w1 : w0;
    u16* dst = GWpk + (long)s * G3 * DP;
    int n = G3 * DP;
    for (int i = blockIdx.x * blockDim.x + threadIdx.x; i < n; i += gridDim.x * blockDim.x){
        int r = i / DP, c = i - r * DP;
        float v = (c < VECT) ? src[r * VECT + c] : 0.f;
        dst[i] = f2bf(v);
    }
}

// ---------------- fused prep: Whh fp32 [384][128] -> fp8, 8-wave gate-permuted rows
// prow = w*48 + g*16 + rr  <->  orig row g*128 + (w*16 + rr)   (w = 0..7)
__global__ __launch_bounds__(256) void cvt_whh2(const float* __restrict__ w0, const float* __restrict__ w1,
                                                u8* __restrict__ dst0)
{
    int s = blockIdx.y;
    const float* src = s ? w1 : w0;
    u8* dst = dst0 + (long)s * G3 * HN;
    int idx = blockIdx.x * 256 + threadIdx.x;
    if (idx >= G3 * HN) return;
    int prow = idx >> 7, col = idx & 127;
    int w  = prow / 48, rem = prow - w * 48;
    int g  = rem >> 4;  int rr = rem & 15;
    int orow = g * 128 + w * 16 + rr;
    int pk = __builtin_amdgcn_cvt_pk_fp8_f32(src[orow * HN + col], 0.f, 0, false);
    dst[idx] = (u8)(pk & 0xFF);
}

// ---------------- GEMM: Y[s][i][col] = sum_d A[s][i][d] * W[wsel][col][d] + bias[col]
// OM: 3 = QKV fused (slices 0,1 row-major bf16, slice 2 transposed);
//     4 = fp32 with GRU gate-permuted columns: col = g*128+i -> i*3+g
template<int NT, int OM, bool WPERSEQ>
__global__ __launch_bounds__(256) void gemm_k(
    const u16* __restrict__ A, const u16* __restrict__ Wp,
    const float* __restrict__ b0, const float* __restrict__ b1, const float* __restrict__ b2,
    int nb, void* __restrict__ Out)
{
    const int lane = threadIdx.x & 63;
    const int wid  = threadIdx.x >> 6;
    const int s    = blockIdx.z;
    const int sl   = blockIdx.y;
    const int wsel = WPERSEQ ? s : sl;
    const int row0 = blockIdx.x * 64 + wid * 16;
    const int m    = lane & 15;
    const int q    = lane >> 4;

    const u16* Arow = A + ((long)s * SEQL + row0) * DP;
    const u16* W    = Wp + (long)wsel * (NT * 16) * DP;

    f32x4 zf = {0.f, 0.f, 0.f, 0.f};
    f32x4 acc[NT];
    #pragma unroll
    for (int n = 0; n < NT; n++) acc[n] = zf;

    for (int c = 0; c < DP / 32; ++c){
        const int koff = c * 32 + q * 8;
        bf16x8 a0 = *(const bf16x8*)(Arow + m * DP + koff);
        #pragma unroll
        for (int n = 0; n < NT; n++){
            bf16x8 b = *(const bf16x8*)(W + (n * 16 + m) * DP + koff);
            acc[n] = MFMA(a0, b, acc[n]);
        }
    }

    const int bsel = WPERSEQ ? s : sl;
    const float* bp = (bsel == 0) ? b0 : ((bsel == 1) ? b1 : b2);
    const long SLC = 2L * SEQL * DP;  // per-slice stride in QKV buffer

    #pragma unroll
    for (int n = 0; n < NT; n++){
        int col = n * 16 + m;
        float bv = (col < nb) ? bp[col] : 0.f;
        #pragma unroll
        for (int r = 0; r < 4; r++){
            long row = row0 + q * 4 + r;
            float v = acc[n][r] + bv;
            if (OM == 4){
                int g = col >> 7, i2 = col & 127;
                long off = ((long)s * SEQL + row) * (long)(NT * 16) + (i2 * 3 + g);
                ((float*)Out)[off] = v;
            } else {  // OM == 3
                long off;
                if (sl < 2) off = ((long)(sl * 2 + s) * SEQL + row) * DP + col;
                else        off = 2 * SLC + ((long)s * DP + col) * SEQL + row;
                ((u16*)Out)[off] = f2bf(v);
            }
        }
    }
}

// ---------------- fused: combine(Onum)+LN1(affine-folded) + W-proj GEMM + residual + LN2
// Per wave (16 rows): stage raw v = sum(Onum)/l + XF as bf16 in a wave-private LDS tile
// (no barrier: wave-wide in-order LDS), collect per-row mean/var; GEMM on raw values with
// W' = g⊙W; epilogue: y = rstd*(acc - mean*gWsum) + bW + w_b + x  -> LN2 -> CUR/XF.
__global__ __launch_bounds__(256) void fuse2_k(
    const u16* __restrict__ Onum, const float* __restrict__ Lp, const float* __restrict__ XF,
    const u16* __restrict__ WLN, const float* __restrict__ gWsum, const float* __restrict__ bW,
    const float* __restrict__ wb,
    const float* __restrict__ res0, const float* __restrict__ res1,
    const float* __restrict__ mg, const float* __restrict__ mb,
    u16* __restrict__ OutB, float* __restrict__ OutF)
{
    const int lane = threadIdx.x & 63;
    const int wid  = threadIdx.x >> 6;
    const int s    = blockIdx.z;
    const int row0 = blockIdx.x * 64 + wid * 16;
    const int m    = lane & 15;
    const int q    = lane >> 4;

    __shared__ __align__(16) u16 At[4][16 * AROW];   // 42 KB, wave-private tiles

    // ---- LN1 phase: lane owns row (row0+m), cols q*80 .. q*80+79
    const long grow = (long)s * SEQL + row0 + m;
    float l = 0.f;
    #pragma unroll
    for (int jc = 0; jc < JC; jc++) l += Lp[(long)jc * 2 * SEQL + grow];
    float inv = 1.f / l;
    const float* xr = XF + grow * DP;
    float sum = 0.f, sq = 0.f;
    #pragma unroll
    for (int i = 0; i < 10; i++){
        int c0 = q * 80 + i * 8;
        float o[8] = {0,0,0,0,0,0,0,0};
        #pragma unroll
        for (int jc = 0; jc < JC; jc++){
            bf16x8 ov = *(const bf16x8*)(Onum + ((long)jc * 2 * SEQL + grow) * DP + c0);
            #pragma unroll
            for (int e = 0; e < 8; e++) o[e] += bf2f(((u16*)&ov)[e]);
        }
        u16 st[8];
        #pragma unroll
        for (int e = 0; e < 8; e++){
            int c = c0 + e;
            float t = (c < VECT) ? (o[e] * inv + xr[c]) : 0.f;
            sum += t; sq += t * t;
            st[e] = f2bf(t);
        }
        *(bf16x8*)(&At[wid][m * AROW + c0]) = *(bf16x8*)st;
    }
    // reduce over the 4 q-lanes of this row
    sum += __shfl_xor(sum, 16); sq += __shfl_xor(sq, 16);
    sum += __shfl_xor(sum, 32); sq += __shfl_xor(sq, 32);
    float mean = sum / VECT;
    float var  = sq / VECT - mean * mean;
    float rstd = rsqrtf(var + 1e-5f);

    // ---- GEMM on raw values (wave-private LDS tile; in-order LDS, no barrier)
    f32x4 zf = {0.f, 0.f, 0.f, 0.f};
    f32x4 acc[NQT];
    #pragma unroll
    for (int n = 0; n < NQT; n++) acc[n] = zf;

    for (int c = 0; c < DP / 32; ++c){
        const int koff = c * 32 + q * 8;
        bf16x8 a0 = *(const bf16x8*)(&At[wid][m * AROW + koff]);
        #pragma unroll
        for (int n = 0; n < NQT; n++){
            bf16x8 bb = *(const bf16x8*)(WLN + (long)(n * 16 + m) * DP + koff);
            acc[n] = MFMA(a0, bb, acc[n]);
        }
    }

    // per-output-row stats (rows q*4+r) fetched from the stats-holder lanes (lane = q*4+r)
    float mean_r[4], rstd_r[4];
    #pragma unroll
    for (int r = 0; r < 4; r++){
        mean_r[r] = __shfl(mean, q * 4 + r);
        rstd_r[r] = __shfl(rstd, q * 4 + r);
    }

    const float* res = s ? res1 : res0;
    float sum2[4] = {0,0,0,0}, sq2[4] = {0,0,0,0};
    #pragma unroll
    for (int n = 0; n < NQT; n++){
        int col = n * 16 + m;
        float gws = gWsum[col];
        float bWv = bW[col];
        float wbv = (col < VECT) ? wb[col] : 0.f;
        #pragma unroll
        for (int r = 0; r < 4; r++){
            long row = row0 + q * 4 + r;
            float rr = (col < VECT) ? res[row * VECT + col] : 0.f;
            float y = rstd_r[r] * (acc[n][r] - mean_r[r] * gws) + bWv + wbv + rr;
            float t = (col < VECT) ? y : 0.f;
            acc[n][r] = t;
            sum2[r] += t; sq2[r] += t * t;
        }
    }
    #pragma unroll
    for (int r = 0; r < 4; r++){
        float su = sum2[r], sv = sq2[r];
        su += __shfl_xor(su, 1); sv += __shfl_xor(sv, 1);
        su += __shfl_xor(su, 2); sv += __shfl_xor(sv, 2);
        su += __shfl_xor(su, 4); sv += __shfl_xor(sv, 4);
        su += __shfl_xor(su, 8); sv += __shfl_xor(sv, 8);
        sum2[r] = su; sq2[r] = sv;
    }
    float mean2[4], rstd2[4];
    #pragma unroll
    for (int r = 0; r < 4; r++){
        mean2[r] = sum2[r] / VECT;
        float v2 = sq2[r] / VECT - mean2[r] * mean2[r];
        rstd2[r] = rsqrtf(v2 + 1e-5f);
    }
    #pragma unroll
    for (int n = 0; n < NQT; n++){
        int col = n * 16 + m;
        float gv = (col < VECT) ? mg[col] : 0.f;
        float bv = (col < VECT) ? mb[col] : 0.f;
        #pragma unroll
        for (int r = 0; r < 4; r++){
            long row = (long)s * SEQL + row0 + q * 4 + r;
            float t = (col < VECT) ? ((acc[n][r] - mean2[r]) * rstd2[r] * gv + bv) : 0.f;
            OutB[row * DP + col] = f2bf(t);
            OutF[row * DP + col] = t;
        }
    }
}

// ---------------- flash attention chunk, LDS-tiled, 2 WGs/CU (r12 config — frozen)
__global__ __launch_bounds__(256, 2) void flash_k(
    const u16* __restrict__ Q, const u16* __restrict__ K, const u16* __restrict__ VT,
    u16* __restrict__ Onum, float* __restrict__ Lp)
{
    const int tid  = threadIdx.x;
    const int lane = tid & 63;
    const int wid  = tid >> 6;
    const int bid  = blockIdx.x;
    const int s    = bid & 1;
    const int jc   = (bid >> 1) & 3;
    const int xi   = bid >> 3;
    const int row0 = xi * 64 + wid * 16;
    const int m = lane & 15, q = lane >> 4;

    __shared__ __align__(16) u16 Kt[32 * KROW];
    __shared__ __align__(16) u16 Vt[DP * VROW];
    __shared__ __align__(16) u16 pb[4][16 * PROW];

    const u16* Qb = Q  + ((long)s * SEQL + row0) * DP;
    const u16* Kc = K  + (long)s * SEQL * DP + (long)jc * 1024 * DP;
    const u16* Vc = VT + (long)s * DP * SEQL + jc * 1024;

    bf16x8 qf[10];
    #pragma unroll
    for (int c = 0; c < 10; c++)
        qf[c] = *(const bf16x8*)(Qb + m * DP + c * 32 + q * 8);

    int skoff[5], wkoff[5], svoff[5], wvoff[5];
    #pragma unroll
    for (int it = 0; it < 5; it++){
        int f  = (it * 256 + tid) * 8;
        int rk = f / 320, ck = f - rk * 320;
        skoff[it] = f;
        wkoff[it] = rk * KROW + ck;
        int rv = f >> 5, cv = f & 31;
        svoff[it] = rv * SEQL + cv;
        wvoff[it] = rv * VROW + cv;
    }

    f32x4 zf = {0.f, 0.f, 0.f, 0.f};
    f32x4 oacc[NQT];
    #pragma unroll
    for (int n = 0; n < NQT; n++) oacc[n] = zf;
    float lacc[4] = {0,0,0,0};

    const float K2 = 0.057735026918962576f * L2E;
    const float MB = -16.f * L2E;

    u32x4 kreg[5], vreg[5];
    #pragma unroll
    for (int it = 0; it < 5; it++){
        kreg[it] = *(const u32x4*)(Kc + skoff[it]);
        vreg[it] = *(const u32x4*)(Vc + svoff[it]);
    }
    #pragma unroll
    for (int it = 0; it < 5; it++){
        *(u32x4*)(&Kt[wkoff[it]]) = kreg[it];
        *(u32x4*)(&Vt[wvoff[it]]) = vreg[it];
    }
    RAW_BAR();

    u16* pbw = &pb[wid][0];

    for (int j = 0; j < 32; ++j){
        if (j + 1 < 32){
            const u16* Kj = Kc + (j + 1) * 32 * DP;
            const u16* Vj = Vc + (j + 1) * 32;
            #pragma unroll
            for (int it = 0; it < 5; it++){
                kreg[it] = *(const u32x4*)(Kj + skoff[it]);
                vreg[it] = *(const u32x4*)(Vj + svoff[it]);
            }
        }
        f32x4 sA = zf, sB = zf;
        #pragma unroll
        for (int c = 0; c < 10; c++){
            bf16x8 kA = *(const bf16x8*)(&Kt[(m     ) * KROW + c * 32 + q * 8]);
            bf16x8 kB = *(const bf16x8*)(&Kt[(m + 16) * KROW + c * 32 + q * 8]);
            sA = MFMA(qf[c], kA, sA);
            sB = MFMA(qf[c], kB, sB);
        }
        #pragma unroll
        for (int r = 0; r < 4; r++){
            float a = __builtin_amdgcn_exp2f(fmaf(sA[r], K2, MB));
            float b = __builtin_amdgcn_exp2f(fmaf(sB[r], K2, MB));
            lacc[r] += a + b;
            pbw[(q * 4 + r) * PROW +      m] = f2bf(a);
            pbw[(q * 4 + r) * PROW + 16 + m] = f2bf(b);
        }
        bf16x8 pf = *(const bf16x8*)(&pbw[m * PROW + q * 8]);
        #pragma unroll
        for (int n = 0; n < NQT; n++){
            bf16x8 vb = *(const bf16x8*)(&Vt[(n * 16 + m) * VROW + q * 8]);
            oacc[n] = MFMA(pf, vb, oacc[n]);
        }
        RAW_BAR();
        if (j + 1 < 32){
            #pragma unroll
            for (int it = 0; it < 5; it++){
                *(u32x4*)(&Kt[wkoff[it]]) = kreg[it];
                *(u32x4*)(&Vt[wvoff[it]]) = vreg[it];
            }
        }
        RAW_BAR();
    }

    #pragma unroll
    for (int r = 0; r < 4; r++){
        float t0 = lacc[r];
        t0 += __shfl_xor(t0, 1); t0 += __shfl_xor(t0, 2);
        t0 += __shfl_xor(t0, 4); t0 += __shfl_xor(t0, 8);
        lacc[r] = t0;
    }
    const long grow0 = (long)s * SEQL + row0;
    if (m == 0){
        #pragma unroll
        for (int r = 0; r < 4; r++)
            Lp[(long)jc * 2 * SEQL + grow0 + q * 4 + r] = lacc[r];
    }
    u16* Ob = Onum + ((long)jc * 2 * SEQL + grow0) * DP;
    #pragma unroll
    for (int n = 0; n < NQT; n++)
        #pragma unroll
        for (int r = 0; r < 4; r++)
            Ob[(long)(q * 4 + r) * DP + n * 16 + m] = f2bf(oacc[n][r]);
}

// ---------------- GRU (r13 config — frozen): 1 WG/seq, 8 waves, ONE raw barrier/step,
// gates in-register via 8-wave gate-permuted fp8 K=128 MFMA; 128 B h exchange.
__global__ __launch_bounds__(512, 1) void gru_k(
    const float* __restrict__ GXP,                         // [2][SEQL][384] fp32, permuted i*3+g
    const u8* __restrict__ Whh8p,                          // [2][384][128] fp8, 8-wave permuted
    const float* __restrict__ Bhh1, const float* __restrict__ Bhh2,
    float* __restrict__ Hout)                              // [2][128] fp32
{
    const int s = blockIdx.x;
    const int tid = threadIdx.x;
    const int lane = tid & 63;
    const int wid  = tid >> 6;                             // 0..7
    const int m = lane & 15, q = lane >> 4;
    const u8* Whh = Whh8p + (long)s * G3 * HN;
    const float* Bhh = s ? Bhh2 : Bhh1;
    const float* gx = GXP + (long)s * SEQL * G3;

    __shared__ __align__(8) u8 hst[2][HN];     // double-buffered fp8 h

    v8i af[3];
    #pragma unroll
    for (int g = 0; g < 3; g++)
        af[g] = *(const v8i*)(Whh + (long)(wid * 48 + g * 16 + m) * HN + q * 32);

    const int rsel = m & 3;
    const int il   = wid * 16 + q * 4 + rsel;
    const int il3  = il * 3;
    const float bhr = Bhh[il], bhz = Bhh[HN + il], bhn = Bhh[2 * HN + il];

    if (tid < HN){ hst[0][tid] = 0; hst[1][tid] = 0; }

    const float* ga = gx + il3;
    float cr0 = ga[0], cz0 = ga[1], cn0 = ga[2];
    const float* gb = gx + G3 + il3;
    float cr1 = gb[0], cz1 = gb[1], cn1 = gb[2];

    __syncthreads();

    float h = 0.f;
    const f32x4 zf = {0.f, 0.f, 0.f, 0.f};

#define GRU_STEP(T, CR, CZ, CN, WB, RB)                                               \
    {                                                                                 \
        v8i bfrag = *(const v8i*)(&hst[RB][q * 32]);                                  \
        f32x4 a0 = __builtin_amdgcn_mfma_scale_f32_16x16x128_f8f6f4(af[0], bfrag, zf, 0, 0, 0, 127, 0, 127); \
        f32x4 a1 = __builtin_amdgcn_mfma_scale_f32_16x16x128_f8f6f4(af[1], bfrag, zf, 0, 0, 0, 127, 0, 127); \
        f32x4 a2 = __builtin_amdgcn_mfma_scale_f32_16x16x128_f8f6f4(af[2], bfrag, zf, 0, 0, 0, 127, 0, 127); \
        float ghr = sel4(a0, rsel);                                                   \
        float ghz = sel4(a1, rsel);                                                   \
        float ghn = sel4(a2, rsel);                                                   \
        float rg = sigm_f(CR + ghr + bhr);                                            \
        float zg = sigm_f(CZ + ghz + bhz);                                            \
        float ng = tanh_f(CN + rg * (ghn + bhn));                                     \
        h = (1.f - zg) * ng + zg * h;                                                 \
        if (m < 4){                                                                   \
            int pk = __builtin_amdgcn_cvt_pk_fp8_f32(h, h, 0, false);                 \
            hst[WB][il] = (u8)(pk & 0xFF);                                            \
        }                                                                             \
        int tp = ((T) + 2 < SEQL) ? (T) + 2 : SEQL - 1;                               \
        const float* gp = gx + (long)tp * G3 + il3;                                   \
        CR = gp[0]; CZ = gp[1]; CN = gp[2];                                           \
        asm volatile("s_waitcnt lgkmcnt(0)" ::: "memory");                            \
        __builtin_amdgcn_s_barrier();                                                 \
        asm volatile("" ::: "memory");                                                \
    }

    for (int t = 0; t < SEQL; t += 2){
        GRU_STEP(t,     cr0, cz0, cn0, 0, 1);
        GRU_STEP(t + 1, cr1, cz1, cn1, 1, 0);
    }
#undef GRU_STEP

    if (m < 4) Hout[s * HN + il] = h;
}

// ---------------- head: fc1+relu, fc2, log_softmax -> 3 fp32
__global__ __launch_bounds__(256) void final_k(const float* __restrict__ Hout,
                                               const float* __restrict__ fc1w, const float* __restrict__ fc1b,
                                               const float* __restrict__ fc2w, const float* __restrict__ fc2b,
                                               float* __restrict__ out)
{
    __shared__ float hb[256];
    __shared__ float r1[256];
    __shared__ float lg[3];
    int tid = threadIdx.x;
    hb[tid] = Hout[tid];
    __syncthreads();
    float a = 0.f;
    for (int k2 = 0; k2 < 256; k2++) a += hb[k2] * fc1w[tid * 256 + k2];
    a += fc1b[tid];
    r1[tid] = fmaxf(a, 0.f);
    __syncthreads();
    if (tid < 3){
        float v = 0.f;
        for (int k2 = 0; k2 < 256; k2++) v += r1[k2] * fc2w[tid * 256 + k2];
        lg[tid] = v + fc2b[tid];
    }
    __syncthreads();
    if (tid == 0){
        float mx = fmaxf(lg[0], fmaxf(lg[1], lg[2]));
        float se = __expf(lg[0] - mx) + __expf(lg[1] - mx) + __expf(lg[2] - mx);
        float ls = mx + logf(se);
        out[0] = lg[0] - ls;
        out[1] = lg[1] - ls;
        out[2] = lg[2] - ls;
    }
}

extern "C" void kernel_launch(void* const* d_in, const int* in_sizes, int n_in,
                              void* d_out, int out_size, void* d_ws, size_t ws_size,
                              hipStream_t stream)
{
    (void)in_sizes; (void)n_in; (void)out_size; (void)ws_size;
    const float* x1     = (const float*)d_in[0];
    const float* x2     = (const float*)d_in[1];
    const float* q_w    = (const float*)d_in[2],  *q_b   = (const float*)d_in[3];
    const float* k_w    = (const float*)d_in[4],  *k_b   = (const float*)d_in[5];
    const float* v_w    = (const float*)d_in[6],  *v_b   = (const float*)d_in[7];
    const float* aln_g  = (const float*)d_in[8],  *aln_b = (const float*)d_in[9];
    const float* w_w    = (const float*)d_in[10], *w_b   = (const float*)d_in[11];
    const float* mln_g  = (const float*)d_in[12], *mln_b = (const float*)d_in[13];
    const float* g1_wih = (const float*)d_in[14], *g1_whh = (const float*)d_in[15];
    const float* g1_bih = (const float*)d_in[16], *g1_bhh = (const float*)d_in[17];
    const float* g2_wih = (const float*)d_in[18], *g2_whh = (const float*)d_in[19];
    const float* g2_bih = (const float*)d_in[20], *g2_bhh = (const float*)d_in[21];
    const float* fc1w   = (const float*)d_in[22], *fc1b  = (const float*)d_in[23];
    const float* fc2w   = (const float*)d_in[24], *fc2b  = (const float*)d_in[25];

    char* wsp = (char*)d_ws;
    auto alloc = [&](size_t bytes) -> char* {
        char* p = wsp; wsp += (bytes + 255) & ~(size_t)255; return p;
    };
    float* XF   = (float*)alloc(2L * SEQL * DP * 4);   // fp32 stack input (residual for aln)
    u16*   CUR  = (u16*)  alloc(2L * SEQL * DP * 2);   // bf16 stack input (MFMA operand)
    u16*   Wpk  = (u16*)  alloc(3L * DP * DP * 2);     // q,k,v packed bf16 [320][320]
    u16*   WLN  = (u16*)  alloc(1L * DP * DP * 2);     // g⊙w_w packed bf16
    float* gWsum= (float*)alloc(DP * 4);
    float* bW   = (float*)alloc(DP * 4);
    u16*   GWpk = (u16*)  alloc(2L * G3 * DP * 2);     // g{1,2}_wih packed bf16 [384][320]
    u8*    Whh8 = (u8*)   alloc(2L * G3 * HN);         // g{1,2}_whh fp8, 8-wave permuted rows
    float* Hout = (float*)alloc(2L * HN * 4);
    float* Lp   = (float*)alloc((long)JC * 2 * SEQL * 4);
    // union1: {QK 2 slices + VT} vs GX (permuted gate-triple layout)
    size_t u1 = (2L * 2 * SEQL * DP + 2L * DP * SEQL) * 2;
    size_t u1b = 2L * SEQL * G3 * 4;
    u16*   QKV  = (u16*)  alloc(u1 > u1b ? u1 : u1b);
    u16*   VT   = QKV + 2L * 2 * SEQL * DP;
    float* GX   = (float*)QKV;
    // union2: Onum (flash numerator partials, bf16)
    u16*   Onum = (u16*)  alloc((long)JC * 2 * SEQL * DP * 2);

    // prep (5 dispatches)
    pad_x2<<<dim3(256, 2), 256, 0, stream>>>(x1, x2, XF, CUR);
    cvt_pad_w3<<<dim3(128, 3), 256, 0, stream>>>(q_w, k_w, v_w, Wpk);
    prep_wln<<<dim3(DP), 320, 0, stream>>>(w_w, aln_g, aln_b, WLN, gWsum, bW);
    cvt_pad_g2<<<dim3(128, 2), 256, 0, stream>>>(g1_wih, g2_wih, GWpk);
    cvt_whh2<<<dim3(192, 2), 256, 0, stream>>>(g1_whh, g2_whh, Whh8);

    for (int st = 0; st < 3; ++st){
        // Q,K -> QKV slices 0,1 ; V -> transposed at slice 2 (VT)
        gemm_k<NQT, 3, false><<<dim3(SEQL / 64, 3, 2), 256, 0, stream>>>(
            CUR, Wpk, q_b, k_b, v_b, VECT, QKV);
        flash_k<<<dim3(512), 256, 0, stream>>>(QKV, QKV + 2L*SEQL*DP, VT, Onum, Lp);
        // fused: combine+LN1(folded) + W-proj + residual(x) + LN2 -> CUR (bf16) + XF (fp32)
        fuse2_k<<<dim3(SEQL / 64, 1, 2), 256, 0, stream>>>(
            Onum, Lp, XF, WLN, gWsum, bW, w_b, x1, x2, mln_g, mln_b, CUR, XF);
    }

    // GRU input projections, gate-permuted output (weight/bias per seq) -> GX
    gemm_k<24, 4, true><<<dim3(SEQL / 64, 1, 2), 256, 0, stream>>>(
        CUR, GWpk, g1_bih, g2_bih, nullptr, G3, GX);
    gru_k<<<dim3(2), 512, 0, stream>>>(GX, Whh8, g1_bhh, g2_bhh, Hout);
    final_k<<<dim3(1), 256, 0, stream>>>(Hout, fc1w, fc1b, fc2w, fc2b, (float*)d_out);
}

// Round 15
// 2015.470 us; speedup vs baseline: 1.0101x; 1.0101x over previous
//
#include <hip/hip_runtime.h>
#include <hip/hip_bf16.h>

// Problem constants
#define SEQL 4096
#define VECT 300
#define DP   320     // padded feature dim (k-dim), 10 chunks of 32
#define NQT  20      // n-tiles (320 cols) for projection GEMMs
#define HN   128
#define G3   384     // 3*H
#define JC   4       // flash j-chunks (split-K over key dim)
#define KROW 328     // LDS K-tile row stride (u16)
#define VROW 40      // LDS VT-tile row stride (u16)
#define PROW 40      // pbuf row stride

typedef unsigned short u16;
typedef unsigned char  u8;
typedef __attribute__((ext_vector_type(8))) short bf16x8;  // 8 bf16 = 4 VGPRs
typedef __attribute__((ext_vector_type(4))) float f32x4;
typedef __attribute__((ext_vector_type(4))) unsigned int u32x4;
typedef __attribute__((ext_vector_type(8))) int   v8i;     // 8 dwords (fp8 x32)

#define MFMA(a,b,c) __builtin_amdgcn_mfma_f32_16x16x32_bf16(a,b,c,0,0,0)
// Verified layouts (learn_hip m89/m91/m120):
//   A[m][k]: m=lane&15, k=(lane>>4)*8+j
//   B[k][n]: n=lane&15, k=(lane>>4)*8+j
//   C/D[row][col]: col=lane&15, row=(lane>>4)*4+reg

#define L2E 1.44269504088896f

#define RAW_BAR() do {                                          \
    asm volatile("s_waitcnt lgkmcnt(0)" ::: "memory");          \
    __builtin_amdgcn_s_barrier();                               \
    asm volatile("" ::: "memory");                              \
} while (0)

__device__ __forceinline__ float bf2f(u16 v){
    union { unsigned u; float f; } t; t.u = ((unsigned)v) << 16; return t.f;
}
__device__ __forceinline__ u16 f2bf(float f){
    union { float f; unsigned u; } t; t.f = f;
    return (u16)((t.u + 0x7FFFu + ((t.u >> 16) & 1u)) >> 16);
}
__device__ __forceinline__ float sigm_f(float x){
    return __builtin_amdgcn_rcpf(1.f + __builtin_amdgcn_exp2f(-L2E * x));
}
__device__ __forceinline__ float tanh_f(float x){
    return fmaf(2.f, __builtin_amdgcn_rcpf(1.f + __builtin_amdgcn_exp2f(-2.f * L2E * x)), -1.f);
}
__device__ __forceinline__ float sel4(f32x4 v, int r){
    float a = (r & 1) ? v.y : v.x;
    float b = (r & 1) ? v.w : v.z;
    return (r & 2) ? b : a;
}

// ---------------- fused prep: x pad (y selects seq)
__global__ __launch_bounds__(256) void pad_x2(const float* __restrict__ x1, const float* __restrict__ x2,
                                              float* __restrict__ xf, u16* __restrict__ cur)
{
    int s = blockIdx.y;
    const float* src = s ? x2 : x1;
    float* xfo = xf + (long)s * SEQL * DP;
    u16*  cro = cur + (long)s * SEQL * DP;
    int n = SEQL * DP;
    for (int i = blockIdx.x * blockDim.x + threadIdx.x; i < n; i += gridDim.x * blockDim.x){
        int r = i / DP, c = i - r * DP;
        float v = (c < VECT) ? src[r * VECT + c] : 0.f;
        xfo[i] = v;
        cro[i] = f2bf(v);
    }
}

// ---------------- fused prep: 4 attention weights -> Wpk (y selects which)
__global__ __launch_bounds__(256) void cvt_pad_w4(const float* __restrict__ w0, const float* __restrict__ w1,
                                                  const float* __restrict__ w2, const float* __restrict__ w3,
                                                  u16* __restrict__ Wpk)
{
    int sl = blockIdx.y;
    const float* src = (sl == 0) ? w0 : (sl == 1) ? w1 : (sl == 2) ? w2 : w3;
    u16* dst = Wpk + (long)sl * DP * DP;
    int n = DP * DP;
    for (int i = blockIdx.x * blockDim.x + threadIdx.x; i < n; i += gridDim.x * blockDim.x){
        int r = i / DP, c = i - r * DP;
        float v = (r < VECT && c < VECT) ? src[r * VECT + c] : 0.f;
        dst[i] = f2bf(v);
    }
}

// ---------------- fused prep: 2 GRU input weights -> GWpk (y selects)
__global__ __launch_bounds__(256) void cvt_pad_g2(const float* __restrict__ w0, const float* __restrict__ w1,
                                                  u16* __restrict__ GWpk)
{
    int s = blockIdx.y;
    const float* src = s ? w1 : w0;
    u16* dst = GWpk + (long)s * G3 * DP;
    int n = G3 * DP;
    for (int i = blockIdx.x * blockDim.x + threadIdx.x; i < n; i += gridDim.x * blockDim.x){
        int r = i / DP, c = i - r * DP;
        float v = (c < VECT) ? src[r * VECT + c] : 0.f;
        dst[i] = f2bf(v);
    }
}

// ---------------- fused prep: Whh fp32 [384][128] -> fp8, 8-wave gate-permuted rows
// prow = w*48 + g*16 + rr  <->  orig row g*128 + (w*16 + rr)   (w = 0..7)
__global__ __launch_bounds__(256) void cvt_whh2(const float* __restrict__ w0, const float* __restrict__ w1,
                                                u8* __restrict__ dst0)
{
    int s = blockIdx.y;
    const float* src = s ? w1 : w0;
    u8* dst = dst0 + (long)s * G3 * HN;
    int idx = blockIdx.x * 256 + threadIdx.x;
    if (idx >= G3 * HN) return;
    int prow = idx >> 7, col = idx & 127;
    int w  = prow / 48, rem = prow - w * 48;
    int g  = rem >> 4;  int rr = rem & 15;
    int orow = g * 128 + w * 16 + rr;
    int pk = __builtin_amdgcn_cvt_pk_fp8_f32(src[orow * HN + col], 0.f, 0, false);
    dst[idx] = (u8)(pk & 0xFF);
}

// ---------------- GEMM: Y[s][i][col] = sum_d A[s][i][d] * W[wsel][col][d] + bias[col]
// 256 thr = 4 waves; wave handles 16 rows; WG = 64 rows.
// OM: 3 = QKV fused (slices 0,1 row-major bf16, slice 2 transposed);
//     4 = fp32 with GRU gate-permuted columns: col = g*128+i -> i*3+g
template<int NT, int OM, bool WPERSEQ>
__global__ __launch_bounds__(256) void gemm_k(
    const u16* __restrict__ A, const u16* __restrict__ Wp,
    const float* __restrict__ b0, const float* __restrict__ b1, const float* __restrict__ b2,
    int nb, void* __restrict__ Out)
{
    const int lane = threadIdx.x & 63;
    const int wid  = threadIdx.x >> 6;
    const int s    = blockIdx.z;
    const int sl   = blockIdx.y;
    const int wsel = WPERSEQ ? s : sl;
    const int row0 = blockIdx.x * 64 + wid * 16;
    const int m    = lane & 15;
    const int q    = lane >> 4;

    const u16* Arow = A + ((long)s * SEQL + row0) * DP;
    const u16* W    = Wp + (long)wsel * (NT * 16) * DP;

    f32x4 zf = {0.f, 0.f, 0.f, 0.f};
    f32x4 acc[NT];
    #pragma unroll
    for (int n = 0; n < NT; n++) acc[n] = zf;

    for (int c = 0; c < DP / 32; ++c){
        const int koff = c * 32 + q * 8;
        bf16x8 a0 = *(const bf16x8*)(Arow + m * DP + koff);
        #pragma unroll
        for (int n = 0; n < NT; n++){
            bf16x8 b = *(const bf16x8*)(W + (n * 16 + m) * DP + koff);
            acc[n] = MFMA(a0, b, acc[n]);
        }
    }

    const int bsel = WPERSEQ ? s : sl;
    const float* bp = (bsel == 0) ? b0 : ((bsel == 1) ? b1 : b2);
    const long SLC = 2L * SEQL * DP;  // per-slice stride in QKV buffer

    #pragma unroll
    for (int n = 0; n < NT; n++){
        int col = n * 16 + m;
        float bv = (col < nb) ? bp[col] : 0.f;
        #pragma unroll
        for (int r = 0; r < 4; r++){
            long row = row0 + q * 4 + r;
            float v = acc[n][r] + bv;
            if (OM == 4){
                int g = col >> 7, i2 = col & 127;
                long off = ((long)s * SEQL + row) * (long)(NT * 16) + (i2 * 3 + g);
                ((float*)Out)[off] = v;
            } else {  // OM == 3
                long off;
                if (sl < 2) off = ((long)(sl * 2 + s) * SEQL + row) * DP + col;
                else        off = 2 * SLC + ((long)s * DP + col) * SEQL + row;
                ((u16*)Out)[off] = f2bf(v);
            }
        }
    }
}

// ---------------- fused W-projection + residual + LayerNorm2:
// CUR/XF[row] = LN(Hb[row] @ W^T + w_b + x[row]) * g + b   (bf16 + fp32 outputs)
__global__ __launch_bounds__(256) void gemmln_k(
    const u16* __restrict__ A, const u16* __restrict__ Wp, const float* __restrict__ bias,
    const float* __restrict__ res0, const float* __restrict__ res1,
    const float* __restrict__ g, const float* __restrict__ b,
    u16* __restrict__ OutB, float* __restrict__ OutF)
{
    const int lane = threadIdx.x & 63;
    const int wid  = threadIdx.x >> 6;
    const int s    = blockIdx.z;
    const int row0 = blockIdx.x * 64 + wid * 16;
    const int m    = lane & 15;
    const int q    = lane >> 4;

    const u16* Arow = A + ((long)s * SEQL + row0) * DP;
    const float* res = s ? res1 : res0;

    f32x4 zf = {0.f, 0.f, 0.f, 0.f};
    f32x4 acc[NQT];
    #pragma unroll
    for (int n = 0; n < NQT; n++) acc[n] = zf;

    for (int c = 0; c < DP / 32; ++c){
        const int koff = c * 32 + q * 8;
        bf16x8 a0 = *(const bf16x8*)(Arow + m * DP + koff);
        #pragma unroll
        for (int n = 0; n < NQT; n++){
            bf16x8 bb = *(const bf16x8*)(Wp + (n * 16 + m) * DP + koff);
            acc[n] = MFMA(a0, bb, acc[n]);
        }
    }

    float sum[4] = {0,0,0,0}, sq[4] = {0,0,0,0};
    #pragma unroll
    for (int n = 0; n < NQT; n++){
        int col = n * 16 + m;
        float bv = (col < VECT) ? bias[col] : 0.f;
        #pragma unroll
        for (int r = 0; r < 4; r++){
            long row = row0 + q * 4 + r;
            float rr = (col < VECT) ? res[row * VECT + col] : 0.f;
            float t = (col < VECT) ? (acc[n][r] + bv + rr) : 0.f;
            acc[n][r] = t;
            sum[r] += t; sq[r] += t * t;
        }
    }
    #pragma unroll
    for (int r = 0; r < 4; r++){
        float su = sum[r], sv = sq[r];
        su += __shfl_xor(su, 1); sv += __shfl_xor(sv, 1);
        su += __shfl_xor(su, 2); sv += __shfl_xor(sv, 2);
        su += __shfl_xor(su, 4); sv += __shfl_xor(sv, 4);
        su += __shfl_xor(su, 8); sv += __shfl_xor(sv, 8);
        sum[r] = su; sq[r] = sv;
    }
    float mean[4], rstd[4];
    #pragma unroll
    for (int r = 0; r < 4; r++){
        mean[r] = sum[r] / VECT;
        float var = sq[r] / VECT - mean[r] * mean[r];
        rstd[r] = rsqrtf(var + 1e-5f);
    }
    #pragma unroll
    for (int n = 0; n < NQT; n++){
        int col = n * 16 + m;
        float gv = (col < VECT) ? g[col] : 0.f;
        float bv = (col < VECT) ? b[col] : 0.f;
        #pragma unroll
        for (int r = 0; r < 4; r++){
            long row = (long)s * SEQL + row0 + q * 4 + r;
            float t = (col < VECT) ? ((acc[n][r] - mean[r]) * rstd[r] * gv + bv) : 0.f;
            OutB[row * DP + col] = f2bf(t);
            OutF[row * DP + col] = t;
        }
    }
}

// ---------------- flash attention chunk, LDS-tiled, 2 WGs/CU (r12 config — frozen)
__global__ __launch_bounds__(256, 2) void flash_k(
    const u16* __restrict__ Q, const u16* __restrict__ K, const u16* __restrict__ VT,
    u16* __restrict__ Onum, float* __restrict__ Lp)
{
    const int tid  = threadIdx.x;
    const int lane = tid & 63;
    const int wid  = tid >> 6;
    const int bid  = blockIdx.x;
    const int s    = bid & 1;
    const int jc   = (bid >> 1) & 3;
    const int xi   = bid >> 3;
    const int row0 = xi * 64 + wid * 16;
    const int m = lane & 15, q = lane >> 4;

    __shared__ __align__(16) u16 Kt[32 * KROW];        // 21.0 KB
    __shared__ __align__(16) u16 Vt[DP * VROW];        // 25.6 KB
    __shared__ __align__(16) u16 pb[4][16 * PROW];     // 5.1 KB

    const u16* Qb = Q  + ((long)s * SEQL + row0) * DP;
    const u16* Kc = K  + (long)s * SEQL * DP + (long)jc * 1024 * DP;
    const u16* Vc = VT + (long)s * DP * SEQL + jc * 1024;

    bf16x8 qf[10];
    #pragma unroll
    for (int c = 0; c < 10; c++)
        qf[c] = *(const bf16x8*)(Qb + m * DP + c * 32 + q * 8);

    int skoff[5], wkoff[5], svoff[5], wvoff[5];
    #pragma unroll
    for (int it = 0; it < 5; it++){
        int f  = (it * 256 + tid) * 8;
        int rk = f / 320, ck = f - rk * 320;
        skoff[it] = f;
        wkoff[it] = rk * KROW + ck;
        int rv = f >> 5, cv = f & 31;
        svoff[it] = rv * SEQL + cv;
        wvoff[it] = rv * VROW + cv;
    }

    f32x4 zf = {0.f, 0.f, 0.f, 0.f};
    f32x4 oacc[NQT];
    #pragma unroll
    for (int n = 0; n < NQT; n++) oacc[n] = zf;
    float lacc[4] = {0,0,0,0};

    const float K2 = 0.057735026918962576f * L2E;
    const float MB = -16.f * L2E;

    u32x4 kreg[5], vreg[5];
    #pragma unroll
    for (int it = 0; it < 5; it++){
        kreg[it] = *(const u32x4*)(Kc + skoff[it]);
        vreg[it] = *(const u32x4*)(Vc + svoff[it]);
    }
    #pragma unroll
    for (int it = 0; it < 5; it++){
        *(u32x4*)(&Kt[wkoff[it]]) = kreg[it];
        *(u32x4*)(&Vt[wvoff[it]]) = vreg[it];
    }
    RAW_BAR();

    u16* pbw = &pb[wid][0];

    for (int j = 0; j < 32; ++j){
        if (j + 1 < 32){
            const u16* Kj = Kc + (j + 1) * 32 * DP;
            const u16* Vj = Vc + (j + 1) * 32;
            #pragma unroll
            for (int it = 0; it < 5; it++){
                kreg[it] = *(const u32x4*)(Kj + skoff[it]);
                vreg[it] = *(const u32x4*)(Vj + svoff[it]);
            }
        }
        f32x4 sA = zf, sB = zf;
        #pragma unroll
        for (int c = 0; c < 10; c++){
            bf16x8 kA = *(const bf16x8*)(&Kt[(m     ) * KROW + c * 32 + q * 8]);
            bf16x8 kB = *(const bf16x8*)(&Kt[(m + 16) * KROW + c * 32 + q * 8]);
            sA = MFMA(qf[c], kA, sA);
            sB = MFMA(qf[c], kB, sB);
        }
        #pragma unroll
        for (int r = 0; r < 4; r++){
            float a = __builtin_amdgcn_exp2f(fmaf(sA[r], K2, MB));
            float b = __builtin_amdgcn_exp2f(fmaf(sB[r], K2, MB));
            lacc[r] += a + b;
            pbw[(q * 4 + r) * PROW +      m] = f2bf(a);
            pbw[(q * 4 + r) * PROW + 16 + m] = f2bf(b);
        }
        bf16x8 pf = *(const bf16x8*)(&pbw[m * PROW + q * 8]);
        #pragma unroll
        for (int n = 0; n < NQT; n++){
            bf16x8 vb = *(const bf16x8*)(&Vt[(n * 16 + m) * VROW + q * 8]);
            oacc[n] = MFMA(pf, vb, oacc[n]);
        }
        RAW_BAR();                    // all waves done reading Kt/Vt for j
        if (j + 1 < 32){
            #pragma unroll
            for (int it = 0; it < 5; it++){
                *(u32x4*)(&Kt[wkoff[it]]) = kreg[it];
                *(u32x4*)(&Vt[wvoff[it]]) = vreg[it];
            }
        }
        RAW_BAR();                    // tiles for j+1 published
    }

    #pragma unroll
    for (int r = 0; r < 4; r++){
        float t0 = lacc[r];
        t0 += __shfl_xor(t0, 1); t0 += __shfl_xor(t0, 2);
        t0 += __shfl_xor(t0, 4); t0 += __shfl_xor(t0, 8);
        lacc[r] = t0;
    }
    const long grow0 = (long)s * SEQL + row0;
    if (m == 0){
        #pragma unroll
        for (int r = 0; r < 4; r++)
            Lp[(long)jc * 2 * SEQL + grow0 + q * 4 + r] = lacc[r];
    }
    u16* Ob = Onum + ((long)jc * 2 * SEQL + grow0) * DP;
    #pragma unroll
    for (int n = 0; n < NQT; n++)
        #pragma unroll
        for (int r = 0; r < 4; r++)
            Ob[(long)(q * 4 + r) * DP + n * 16 + m] = f2bf(oacc[n][r]);
}

// ---------------- combine chunks + LayerNorm1: out = LN(sum(Onum)/sum(l) + XF) * g + b
__global__ __launch_bounds__(256) void lncomb_k(const u16* __restrict__ Onum, const float* __restrict__ Lp,
                                                const float* __restrict__ XF,
                                                const float* __restrict__ g, const float* __restrict__ b,
                                                u16* __restrict__ OutB)
{
    long row = (long)((blockIdx.x * blockDim.x + threadIdx.x) >> 6);
    int lane = threadIdx.x & 63;
    if (row >= 2L * SEQL) return;
    float l = 0.f;
    #pragma unroll
    for (int jc = 0; jc < JC; jc++) l += Lp[(long)jc * 2 * SEQL + row];
    float inv = 1.f / l;
    const float* xr = XF + row * DP;
    float v[5], sum = 0.f, sq = 0.f;
    #pragma unroll
    for (int i = 0; i < 5; i++){
        int c = lane + i * 64;
        float o = 0.f;
        #pragma unroll
        for (int jc = 0; jc < JC; jc++)
            o += bf2f(Onum[((long)jc * 2 * SEQL + row) * DP + c]);
        float t = (c < VECT) ? (o * inv + xr[c]) : 0.f;
        v[i] = t; sum += t; sq += t * t;
    }
    #pragma unroll
    for (int o = 1; o < 64; o <<= 1){ sum += __shfl_xor(sum, o); sq += __shfl_xor(sq, o); }
    float mean = sum / VECT;
    float var  = sq / VECT - mean * mean;
    float rstd = rsqrtf(var + 1e-5f);
    #pragma unroll
    for (int i = 0; i < 5; i++){
        int c = lane + i * 64;
        float t = (c < VECT) ? ((v[i] - mean) * rstd * g[c] + b[c]) : 0.f;
        OutB[row * DP + c] = f2bf(t);
    }
}

// ---------------- GRU (r13 config — frozen): 1 WG/seq, 8 waves, ONE raw barrier/step,
// gates in-register via 8-wave gate-permuted fp8 K=128 MFMA; 128 B h exchange.
__global__ __launch_bounds__(512, 1) void gru_k(
    const float* __restrict__ GXP,                         // [2][SEQL][384] fp32, permuted i*3+g
    const u8* __restrict__ Whh8p,                          // [2][384][128] fp8, 8-wave permuted
    const float* __restrict__ Bhh1, const float* __restrict__ Bhh2,
    float* __restrict__ Hout)                              // [2][128] fp32
{
    const int s = blockIdx.x;
    const int tid = threadIdx.x;
    const int lane = tid & 63;
    const int wid  = tid >> 6;                             // 0..7
    const int m = lane & 15, q = lane >> 4;
    const u8* Whh = Whh8p + (long)s * G3 * HN;
    const float* Bhh = s ? Bhh2 : Bhh1;
    const float* gx = GXP + (long)s * SEQL * G3;

    __shared__ __align__(8) u8 hst[2][HN];     // double-buffered fp8 h

    v8i af[3];
    #pragma unroll
    for (int g = 0; g < 3; g++)
        af[g] = *(const v8i*)(Whh + (long)(wid * 48 + g * 16 + m) * HN + q * 32);

    const int rsel = m & 3;
    const int il   = wid * 16 + q * 4 + rsel;
    const int il3  = il * 3;
    const float bhr = Bhh[il], bhz = Bhh[HN + il], bhn = Bhh[2 * HN + il];

    if (tid < HN){ hst[0][tid] = 0; hst[1][tid] = 0; }

    const float* ga = gx + il3;
    float cr0 = ga[0], cz0 = ga[1], cn0 = ga[2];
    const float* gb = gx + G3 + il3;
    float cr1 = gb[0], cz1 = gb[1], cn1 = gb[2];

    __syncthreads();

    float h = 0.f;
    const f32x4 zf = {0.f, 0.f, 0.f, 0.f};

#define GRU_STEP(T, CR, CZ, CN, WB, RB)                                               \
    {                                                                                 \
        v8i bfrag = *(const v8i*)(&hst[RB][q * 32]);                                  \
        f32x4 a0 = __builtin_amdgcn_mfma_scale_f32_16x16x128_f8f6f4(af[0], bfrag, zf, 0, 0, 0, 127, 0, 127); \
        f32x4 a1 = __builtin_amdgcn_mfma_scale_f32_16x16x128_f8f6f4(af[1], bfrag, zf, 0, 0, 0, 127, 0, 127); \
        f32x4 a2 = __builtin_amdgcn_mfma_scale_f32_16x16x128_f8f6f4(af[2], bfrag, zf, 0, 0, 0, 127, 0, 127); \
        float ghr = sel4(a0, rsel);                                                   \
        float ghz = sel4(a1, rsel);                                                   \
        float ghn = sel4(a2, rsel);                                                   \
        float rg = sigm_f(CR + ghr + bhr);                                            \
        float zg = sigm_f(CZ + ghz + bhz);                                            \
        float ng = tanh_f(CN + rg * (ghn + bhn));                                     \
        h = (1.f - zg) * ng + zg * h;                                                 \
        if (m < 4){                                                                   \
            int pk = __builtin_amdgcn_cvt_pk_fp8_f32(h, h, 0, false);                 \
            hst[WB][il] = (u8)(pk & 0xFF);                                            \
        }                                                                             \
        int tp = ((T) + 2 < SEQL) ? (T) + 2 : SEQL - 1;                               \
        const float* gp = gx + (long)tp * G3 + il3;                                   \
        CR = gp[0]; CZ = gp[1]; CN = gp[2];                                           \
        asm volatile("s_waitcnt lgkmcnt(0)" ::: "memory");                            \
        __builtin_amdgcn_s_barrier();                                                 \
        asm volatile("" ::: "memory");                                                \
    }

    for (int t = 0; t < SEQL; t += 2){
        GRU_STEP(t,     cr0, cz0, cn0, 0, 1);
        GRU_STEP(t + 1, cr1, cz1, cn1, 1, 0);
    }
#undef GRU_STEP

    if (m < 4) Hout[s * HN + il] = h;
}

// ---------------- head: fc1+relu, fc2, log_softmax -> 3 fp32
__global__ __launch_bounds__(256) void final_k(const float* __restrict__ Hout,
                                               const float* __restrict__ fc1w, const float* __restrict__ fc1b,
                                               const float* __restrict__ fc2w, const float* __restrict__ fc2b,
                                               float* __restrict__ out)
{
    __shared__ float hb[256];
    __shared__ float r1[256];
    __shared__ float lg[3];
    int tid = threadIdx.x;
    hb[tid] = Hout[tid];
    __syncthreads();
    float a = 0.f;
    for (int k2 = 0; k2 < 256; k2++) a += hb[k2] * fc1w[tid * 256 + k2];
    a += fc1b[tid];
    r1[tid] = fmaxf(a, 0.f);
    __syncthreads();
    if (tid < 3){
        float v = 0.f;
        for (int k2 = 0; k2 < 256; k2++) v += r1[k2] * fc2w[tid * 256 + k2];
        lg[tid] = v + fc2b[tid];
    }
    __syncthreads();
    if (tid == 0){
        float mx = fmaxf(lg[0], fmaxf(lg[1], lg[2]));
        float se = __expf(lg[0] - mx) + __expf(lg[1] - mx) + __expf(lg[2] - mx);
        float ls = mx + logf(se);
        out[0] = lg[0] - ls;
        out[1] = lg[1] - ls;
        out[2] = lg[2] - ls;
    }
}

extern "C" void kernel_launch(void* const* d_in, const int* in_sizes, int n_in,
                              void* d_out, int out_size, void* d_ws, size_t ws_size,
                              hipStream_t stream)
{
    (void)in_sizes; (void)n_in; (void)out_size; (void)ws_size;
    const float* x1     = (const float*)d_in[0];
    const float* x2     = (const float*)d_in[1];
    const float* q_w    = (const float*)d_in[2],  *q_b   = (const float*)d_in[3];
    const float* k_w    = (const float*)d_in[4],  *k_b   = (const float*)d_in[5];
    const float* v_w    = (const float*)d_in[6],  *v_b   = (const float*)d_in[7];
    const float* aln_g  = (const float*)d_in[8],  *aln_b = (const float*)d_in[9];
    const float* w_w    = (const float*)d_in[10], *w_b   = (const float*)d_in[11];
    const float* mln_g  = (const float*)d_in[12], *mln_b = (const float*)d_in[13];
    const float* g1_wih = (const float*)d_in[14], *g1_whh = (const float*)d_in[15];
    const float* g1_bih = (const float*)d_in[16], *g1_bhh = (const float*)d_in[17];
    const float* g2_wih = (const float*)d_in[18], *g2_whh = (const float*)d_in[19];
    const float* g2_bih = (const float*)d_in[20], *g2_bhh = (const float*)d_in[21];
    const float* fc1w   = (const float*)d_in[22], *fc1b  = (const float*)d_in[23];
    const float* fc2w   = (const float*)d_in[24], *fc2b  = (const float*)d_in[25];

    char* wsp = (char*)d_ws;
    auto alloc = [&](size_t bytes) -> char* {
        char* p = wsp; wsp += (bytes + 255) & ~(size_t)255; return p;
    };
    float* XF   = (float*)alloc(2L * SEQL * DP * 4);   // fp32 stack input (residual for aln)
    u16*   CUR  = (u16*)  alloc(2L * SEQL * DP * 2);   // bf16 stack input (MFMA operand)
    u16*   Hb   = (u16*)  alloc(2L * SEQL * DP * 2);   // LN1 output bf16
    u16*   Wpk  = (u16*)  alloc(4L * DP * DP * 2);     // q,k,v,w packed bf16 [320][320]
    u16*   GWpk = (u16*)  alloc(2L * G3 * DP * 2);     // g{1,2}_wih packed bf16 [384][320]
    u8*    Whh8 = (u8*)   alloc(2L * G3 * HN);         // g{1,2}_whh fp8, 8-wave permuted rows
    float* Hout = (float*)alloc(2L * HN * 4);
    float* Lp   = (float*)alloc((long)JC * 2 * SEQL * 4);
    // union1: {QK 2 slices + VT} vs GX (permuted gate-triple layout)
    size_t u1 = (2L * 2 * SEQL * DP + 2L * DP * SEQL) * 2;
    size_t u1b = 2L * SEQL * G3 * 4;
    u16*   QKV  = (u16*)  alloc(u1 > u1b ? u1 : u1b);
    u16*   VT   = QKV + 2L * 2 * SEQL * DP;
    float* GX   = (float*)QKV;
    // union2: Onum (flash numerator partials, bf16)
    u16*   Onum = (u16*)  alloc((long)JC * 2 * SEQL * DP * 2);

    // prep (4 dispatches)
    pad_x2<<<dim3(256, 2), 256, 0, stream>>>(x1, x2, XF, CUR);
    cvt_pad_w4<<<dim3(128, 4), 256, 0, stream>>>(q_w, k_w, v_w, w_w, Wpk);
    cvt_pad_g2<<<dim3(128, 2), 256, 0, stream>>>(g1_wih, g2_wih, GWpk);
    cvt_whh2<<<dim3(192, 2), 256, 0, stream>>>(g1_whh, g2_whh, Whh8);

    for (int st = 0; st < 3; ++st){
        // Q,K -> QKV slices 0,1 ; V -> transposed at slice 2 (VT)
        gemm_k<NQT, 3, false><<<dim3(SEQL / 64, 3, 2), 256, 0, stream>>>(
            CUR, Wpk, q_b, k_b, v_b, VECT, QKV);
        flash_k<<<dim3(512), 256, 0, stream>>>(QKV, QKV + 2L*SEQL*DP, VT, Onum, Lp);
        lncomb_k<<<dim3(2 * SEQL / 4), 256, 0, stream>>>(Onum, Lp, XF, aln_g, aln_b, Hb);
        // fused: W-proj + residual(x) + LN2 -> CUR (bf16) + XF (fp32)
        gemmln_k<<<dim3(SEQL / 64, 1, 2), 256, 0, stream>>>(
            Hb, Wpk + 3L * DP * DP, w_b, x1, x2, mln_g, mln_b, CUR, XF);
    }

    // GRU input projections, gate-permuted output (weight/bias per seq) -> GX
    gemm_k<24, 4, true><<<dim3(SEQL / 64, 1, 2), 256, 0, stream>>>(
        CUR, GWpk, g1_bih, g2_bih, nullptr, G3, GX);
    gru_k<<<dim3(2), 512, 0, stream>>>(GX, Whh8, g1_bhh, g2_bhh, Hout);
    final_k<<<dim3(1), 256, 0, stream>>>(Hout, fc1w, fc1b, fc2w, fc2b, (float*)d_out);
}